// Round 3
// baseline (201.405 us; speedup 1.0000x reference)
//
#include <hip/hip_runtime.h>

// Problem constants (from reference)
#define KSIZE   32
#define KSTRIDE 16
#define HK      4
#define HD      128
#define ROW     (HK * HD)                       // 512 floats per token
#define ROW4    (ROW / 4)                       // 128 float4 per token
#define BATCH   4
#define SEQLEN  16384
#define CHUNKS_PER_BATCH ((SEQLEN - KSIZE) / KSTRIDE + 1)   // 1023
#define TOTAL_CHUNKS     (BATCH * CHUNKS_PER_BATCH)         // 4092

// G consecutive chunks per group: reads (G+1)*16 rows for G outputs.
// G=11 divides 1023 (= 3*11*31): 93 groups/batch, 372 groups total.
// Each group's 128 float4 columns are split across 2 single-wave blocks
// (64 lanes x 1 float4 column each) -> 744 blocks of exactly 1 wave:
// fine scheduling granularity for tail balance, perfectly coalesced
// 1 KiB-per-instruction contiguous loads.
#define G 11
#define GROUPS_PER_BATCH (CHUNKS_PER_BATCH / G)             // 93
#define TOTAL_GROUPS     (BATCH * GROUPS_PER_BATCH)         // 372
#define TOTAL_BLOCKS     (TOTAL_GROUPS * 2)                 // 744

__global__ __launch_bounds__(64)
void compress_k_fused(const float* __restrict__ k,
                      const int* __restrict__ cu_seqlens,
                      float* __restrict__ out,
                      float* __restrict__ tail) {
    const int blk = blockIdx.x;
    const int grp = blk >> 1;          // group id 0..371
    const int h   = blk & 1;           // column half: 0 -> cols [0,64), 1 -> [64,128)
    const int b   = grp / GROUPS_PER_BATCH;
    const int gb  = grp - b * GROUPS_PER_BATCH;
    const int c0  = gb * G;            // first chunk within batch

    const long start_row = (long)cu_seqlens[b] + (long)c0 * KSTRIDE;
    const int t = threadIdx.x;         // 0..63
    const int col = h * 64 + t;        // float4 column 0..127
    const float4* __restrict__ src = (const float4*)(k + start_row * ROW) + col;

    // G+1 half-window sums (16 rows each) -> 12 independent chains.
    float4 hs[G + 1];
    #pragma unroll
    for (int j = 0; j <= G; ++j) hs[j] = make_float4(0.f, 0.f, 0.f, 0.f);

    #pragma unroll
    for (int j = 0; j <= G; ++j) {
        #pragma unroll
        for (int i = 0; i < KSTRIDE; ++i) {
            float4 v = src[(long)(j * KSTRIDE + i) * ROW4];
            hs[j].x += v.x; hs[j].y += v.y; hs[j].z += v.z; hs[j].w += v.w;
        }
    }

    const float s = 1.0f / (float)KSIZE;
    const int chunk0 = b * CHUNKS_PER_BATCH + c0;
    #pragma unroll
    for (int g = 0; g < G; ++g) {
        float4 r = make_float4((hs[g].x + hs[g + 1].x) * s,
                               (hs[g].y + hs[g + 1].y) * s,
                               (hs[g].z + hs[g + 1].z) * s,
                               (hs[g].w + hs[g + 1].w) * s);
        ((float4*)(out + (long)(chunk0 + g) * ROW))[col] = r;
    }

    // Fused cu_comp tail write (fp32 values in the flat out buffer).
    if (blk == 0 && t == 0) {
        int run = 0;
        tail[0] = 0.0f;
        #pragma unroll
        for (int i = 0; i < BATCH; ++i) {
            const int len = cu_seqlens[i + 1] - cu_seqlens[i];
            const int n = (len >= KSIZE) ? (len - KSIZE) / KSTRIDE + 1 : 0;
            run += n;
            tail[i + 1] = (float)run;
        }
    }
}

extern "C" void kernel_launch(void* const* d_in, const int* in_sizes, int n_in,
                              void* d_out, int out_size, void* d_ws, size_t ws_size,
                              hipStream_t stream) {
    const float* k          = (const float*)d_in[0];
    const int*   cu_seqlens = (const int*)d_in[1];
    float*       out        = (float*)d_out;
    float*       tail       = out + (long)TOTAL_CHUNKS * ROW;

    compress_k_fused<<<TOTAL_BLOCKS, 64, 0, stream>>>(k, cu_seqlens, out, tail);
}

// Round 5
// 200.118 us; speedup vs baseline: 1.0064x; 1.0064x over previous
//
#include <hip/hip_runtime.h>

// Problem constants (from reference)
#define KSIZE   32
#define KSTRIDE 16
#define HK      4
#define HD      128
#define ROW     (HK * HD)                       // 512 floats per token
#define ROW4    (ROW / 4)                       // 128 float4 per token
#define BATCH   4
#define SEQLEN  16384
#define CHUNKS_PER_BATCH ((SEQLEN - KSIZE) / KSTRIDE + 1)   // 1023
#define TOTAL_CHUNKS     (BATCH * CHUNKS_PER_BATCH)         // 4092

// Native vector type for nontemporal builtins (HIP_vector_type is rejected).
typedef float vfloat4 __attribute__((ext_vector_type(4)));

// G=3: best measured traffic/parallelism tradeoff (G=1:197.4, G=3:194.7,
// G=11:201.4 us). 1364 groups x 2 waves = 2728 waves (10.7/CU).
#define G 3
#define GROUPS_PER_BATCH (CHUNKS_PER_BATCH / G)             // 341
#define TOTAL_GROUPS     (BATCH * GROUPS_PER_BATCH)         // 1364

// XCD swizzle: physical block p lands on XCD p%8 (round-robin dispatch).
// Map physical -> logical so each XCD owns a CONTIGUOUS run of groups:
// adjacent groups share a 16-row boundary half-window, which then hits the
// same XCD's L2 instead of bouncing through the die-level LLC.
#define NXCD 8
#define GROUPS_PER_XCD ((TOTAL_GROUPS + NXCD - 1) / NXCD)   // 171
#define LAUNCH_BLOCKS  (GROUPS_PER_XCD * NXCD)              // 1368 (4 idle)

__global__ __launch_bounds__(128)
void compress_k_fused(const float* __restrict__ k,
                      const int* __restrict__ cu_seqlens,
                      float* __restrict__ out,
                      float* __restrict__ tail) {
    const int p   = blockIdx.x;
    const int grp = (p % NXCD) * GROUPS_PER_XCD + (p / NXCD);   // logical group

    // Fused cu_comp tail write (fp32 values in the flat out buffer).
    if (p == 0 && threadIdx.x == 0) {
        int run = 0;
        tail[0] = 0.0f;
        #pragma unroll
        for (int i = 0; i < BATCH; ++i) {
            const int len = cu_seqlens[i + 1] - cu_seqlens[i];
            const int n = (len >= KSIZE) ? (len - KSIZE) / KSTRIDE + 1 : 0;
            run += n;
            tail[i + 1] = (float)run;
        }
    }

    if (grp >= TOTAL_GROUPS) return;   // swizzle padding blocks

    const int b  = grp / GROUPS_PER_BATCH;
    const int gb = grp - b * GROUPS_PER_BATCH;
    const int c0 = gb * G;                         // first chunk within batch

    const long start_row = (long)cu_seqlens[b] + (long)c0 * KSTRIDE;
    const vfloat4* __restrict__ src = (const vfloat4*)(k + start_row * ROW);
    const int t = threadIdx.x;   // 0..127, owns float4 column t

    // G+1 half-window sums (16 rows each), independent accumulation chains.
    vfloat4 h[G + 1];
    #pragma unroll
    for (int j = 0; j <= G; ++j) h[j] = (vfloat4)(0.f);

    #pragma unroll
    for (int j = 0; j <= G; ++j) {
        #pragma unroll
        for (int i = 0; i < KSTRIDE; ++i) {
            h[j] += src[(long)(j * KSTRIDE + i) * ROW4 + t];
        }
    }

    const float s = 1.0f / (float)KSIZE;
    const int chunk0 = b * CHUNKS_PER_BATCH + c0;
    #pragma unroll
    for (int g = 0; g < G; ++g) {
        vfloat4 r = (h[g] + h[g + 1]) * s;
        // Non-temporal: output is write-once, never re-read by this kernel.
        __builtin_nontemporal_store(r, (vfloat4*)(out + (long)(chunk0 + g) * ROW) + t);
    }
}

extern "C" void kernel_launch(void* const* d_in, const int* in_sizes, int n_in,
                              void* d_out, int out_size, void* d_ws, size_t ws_size,
                              hipStream_t stream) {
    const float* k          = (const float*)d_in[0];
    const int*   cu_seqlens = (const int*)d_in[1];
    float*       out        = (float*)d_out;
    float*       tail       = out + (long)TOTAL_CHUNKS * ROW;

    compress_k_fused<<<LAUNCH_BLOCKS, 128, 0, stream>>>(k, cu_seqlens, out, tail);
}

// Round 6
// 196.680 us; speedup vs baseline: 1.0240x; 1.0175x over previous
//
#include <hip/hip_runtime.h>

// Problem constants (from reference)
#define KSIZE   32
#define KSTRIDE 16
#define HK      4
#define HD      128
#define ROW     (HK * HD)                       // 512 floats per token
#define ROW4    (ROW / 4)                       // 128 float4 per token
#define BATCH   4
#define SEQLEN  16384
#define CHUNKS_PER_BATCH ((SEQLEN - KSIZE) / KSTRIDE + 1)   // 1023
#define TOTAL_CHUNKS     (BATCH * CHUNKS_PER_BATCH)         // 4092

// G=3: best measured traffic/parallelism tradeoff across the session
// (G=1: 197.4, G=3: 194.7, G=11: 201.4, G=3+XCD-swizzle+NT: 200.1 us).
// 1364 blocks x 2 waves = 2728 waves (10.7/CU) — enough TLP to saturate BW;
// (G+1)*16 = 64 rows read per 3 chunks (vs 96 naive) trims duplicate reads
// while default back-to-back dispatch keeps boundary half-windows L2-warm.
#define G 3
#define BLOCKS_PER_BATCH (CHUNKS_PER_BATCH / G)             // 341
#define TOTAL_BLOCKS     (BATCH * BLOCKS_PER_BATCH)         // 1364

__global__ __launch_bounds__(128)
void compress_k_fused(const float* __restrict__ k,
                      const int* __restrict__ cu_seqlens,
                      float* __restrict__ out,
                      float* __restrict__ tail) {
    const int blk = blockIdx.x;
    const int b   = blk / BLOCKS_PER_BATCH;
    const int cb  = blk - b * BLOCKS_PER_BATCH;   // block index within batch
    const int c0  = cb * G;                        // first chunk (within batch)

    const long start_row = (long)cu_seqlens[b] + (long)c0 * KSTRIDE;
    const float4* __restrict__ src = (const float4*)(k + start_row * ROW);
    const int t = threadIdx.x;   // 0..127, owns float4 column t

    // G+1 half-window sums (16 rows each), independent accumulation chains.
    float4 h[G + 1];
    #pragma unroll
    for (int j = 0; j <= G; ++j) h[j] = make_float4(0.f, 0.f, 0.f, 0.f);

    #pragma unroll
    for (int j = 0; j <= G; ++j) {
        #pragma unroll
        for (int i = 0; i < KSTRIDE; ++i) {
            float4 v = src[(long)(j * KSTRIDE + i) * ROW4 + t];
            h[j].x += v.x; h[j].y += v.y; h[j].z += v.z; h[j].w += v.w;
        }
    }

    const float s = 1.0f / (float)KSIZE;
    const int chunk0 = b * CHUNKS_PER_BATCH + c0;
    #pragma unroll
    for (int g = 0; g < G; ++g) {
        float4 r = make_float4((h[g].x + h[g + 1].x) * s,
                               (h[g].y + h[g + 1].y) * s,
                               (h[g].z + h[g + 1].z) * s,
                               (h[g].w + h[g + 1].w) * s);
        ((float4*)(out + (long)(chunk0 + g) * ROW))[t] = r;
    }

    // Fused cu_comp tail write (fp32 values in the flat out buffer).
    if (blk == 0 && t == 0) {
        int run = 0;
        tail[0] = 0.0f;
        #pragma unroll
        for (int i = 0; i < BATCH; ++i) {
            const int len = cu_seqlens[i + 1] - cu_seqlens[i];
            const int n = (len >= KSIZE) ? (len - KSIZE) / KSTRIDE + 1 : 0;
            run += n;
            tail[i + 1] = (float)run;
        }
    }
}

extern "C" void kernel_launch(void* const* d_in, const int* in_sizes, int n_in,
                              void* d_out, int out_size, void* d_ws, size_t ws_size,
                              hipStream_t stream) {
    const float* k          = (const float*)d_in[0];
    const int*   cu_seqlens = (const int*)d_in[1];
    float*       out        = (float*)d_out;
    float*       tail       = out + (long)TOTAL_CHUNKS * ROW;

    compress_k_fused<<<TOTAL_BLOCKS, 128, 0, stream>>>(k, cu_seqlens, out, tail);
}